// Round 16
// baseline (141.332 us; speedup 1.0000x reference)
//
#include <hip/hip_runtime.h>
#include <stdint.h>

typedef _Float16 half8 __attribute__((ext_vector_type(8)));
typedef float f32x4 __attribute__((ext_vector_type(4)));

#define MFMA_F16(A, B, C) __builtin_amdgcn_mfma_f32_16x16x32_f16(A, B, C, 0, 0, 0)

// ws layout (bytes):
//   wgi  fp16[12jt*4kt*64*8] @ 0       (49152)  frag-packed W_comb = W_ih @ W_enc
//   whhp fp16[12jt*2kt*64*8] @ 49152   (24576)  frag-packed W_hh
//   bc   f32[192]            @ 73728   (768)    combined gi bias = W_ih@b_enc + b_ih
//   genc f32[1024*64]        @ 74752   (262144)

// ---------------- Kernel 0: prep — W_comb + frag-packing (24 x 256) ----------------
__global__ __launch_bounds__(256) void k_prep(const float* __restrict__ Wenc,
                                              const float* __restrict__ benc,
                                              const float* __restrict__ Wih,
                                              const float* __restrict__ Whh,
                                              const float* __restrict__ bih,
                                              _Float16* __restrict__ wgi,
                                              _Float16* __restrict__ whhp,
                                              float* __restrict__ bc) {
  __shared__ float wenc_s[64 * 68];  // k-half of Wenc, padded
  __shared__ float wih_s[16 * 64];   // this block's 16 Wih rows
  const int t = threadIdx.x;
  const int bt = blockIdx.x;
  const int jt = bt >> 1, kh = (bt & 1) << 6;

  for (int i = t; i < 4096; i += 256)
    wenc_s[(i >> 6) * 68 + (i & 63)] = Wenc[(i >> 6) * 128 + kh + (i & 63)];
  for (int i = t; i < 1024; i += 256)
    wih_s[i] = Wih[(jt * 16 + (i >> 6)) * 64 + (i & 63)];
  __syncthreads();

  const int jl = t >> 4, kb = (t & 15) * 4;
  f32x4 acc = (f32x4){0.f, 0.f, 0.f, 0.f};
  for (int m = 0; m < 64; ++m) {
    float w = wih_s[jl * 64 + m];
    f32x4 v = *(const f32x4*)&wenc_s[m * 68 + kb];
    acc[0] += w * v[0]; acc[1] += w * v[1];
    acc[2] += w * v[2]; acc[3] += w * v[3];
  }
#pragma unroll
  for (int i = 0; i < 4; ++i) {
    int k = kh + kb + i;  // frag map: tile jt*4+kt, lane g*16+(j&15), elem k&7
    wgi[((jt * 4 + (k >> 5)) * 64 + ((k >> 3) & 3) * 16 + jl) * 8 + (k & 7)] =
        (_Float16)acc[i];
  }

  if ((bt & 1) == 0) {
#pragma unroll
    for (int i = 0; i < 4; ++i) {
      int idx = t * 4 + i;
      int j = jt * 16 + (idx >> 6), k = idx & 63;
      whhp[((jt * 2 + (k >> 5)) * 64 + ((k >> 3) & 3) * 16 + (j & 15)) * 8 + (k & 7)] =
          (_Float16)Whh[j * 64 + k];
    }
    if (t < 16) {
      int j = jt * 16 + t;
      float s = bih[j];
      for (int m = 0; m < 64; ++m) s += wih_s[t * 64 + m] * benc[m];
      bc[j] = s;
    }
  }
}

// ---------------- Kernel 1: FUSED encoder+GRU+pooling ----------------
// v3 skeleton (512 blocks x 512 thr, 2 graphs, wave p owns 16 cols/gate, raw
// per-step barrier). x gathered RAW (K=128, combined weights): each of a
// graph's 4 waves loads/converts only k-quarter p of the 16 walk rows into a
// double-buffered swizzled LDS x-stage; all 4 waves read their A-frags from it.
__global__ __launch_bounds__(512, 4) void k_gru(const float* __restrict__ x,
                                                const int* __restrict__ walks,
                                                const _Float16* __restrict__ wgi,
                                                const _Float16* __restrict__ whhp,
                                                const float* __restrict__ bc,
                                                const float* __restrict__ bhh,
                                                float* __restrict__ genc) {
  __shared__ _Float16 xs[2][2][2048];    // [graph][buf][16 rows x 128 k] 16 KB
  __shared__ _Float16 h_lds[2][2][1024]; // [graph][buf] 8 KB
  __shared__ int ids[2][256];

  const int tid = threadIdx.x;
  const int lane = tid & 63, wv = tid >> 6;
  const int r = lane & 15, g = lane >> 4;
  const int p = wv & 3, gl = wv >> 2;
  const int gph = blockIdx.x * 2 + gl;

  // weights straight from ws (already frag-packed -> coalesced b128 reads)
  half8 Bi[3][4], Bh[3][2];
#pragma unroll
  for (int G = 0; G < 3; ++G) {
#pragma unroll
    for (int kt = 0; kt < 4; ++kt)
      Bi[G][kt] = *(const half8*)&wgi[(((G * 4 + p) * 4 + kt) * 64 + lane) * 8];
#pragma unroll
    for (int kt = 0; kt < 2; ++kt)
      Bh[G][kt] = *(const half8*)&whhp[(((G * 4 + p) * 2 + kt) * 64 + lane) * 8];
  }

  if ((wv & 3) == 0) {  // waves 0/4 stage the two graphs' ids, transposed
    const int* wp = walks + gph * 256;
    int4 v = *(const int4*)(wp + lane * 4);
    int vals[4] = {v.x, v.y, v.z, v.w};
#pragma unroll
    for (int i = 0; i < 4; ++i) {
      int m = lane * 4 + i;  // m = w*16 + t
      ids[gl][(m & 15) * 16 + (m >> 4)] = vals[i];
    }
  }
  for (int i = tid; i < 4096; i += 512) ((_Float16*)h_lds)[i] = (_Float16)0.f;
  __syncthreads();

  const int j0 = p * 16 + r;
  const float br_ = bc[j0] + bhh[j0];
  const float bz_ = bc[64 + j0] + bhh[64 + j0];
  const float bin_ = bc[128 + j0];
  const float bhn_ = bhh[128 + j0];
  const int swz = (r & 7) << 4;

  char* xg = (char*)&xs[gl][0][0];
  char* hg = (char*)&h_lds[gl][0][0];
  const int xwb = r * 256 + ((p * 64 + g * 16) ^ swz);  // this wave's stage slot

  // prologue: stage xs for t=0,1 (wave p loads its k-quarter of all 16 rows)
#pragma unroll
  for (int tt = 0; tt < 2; ++tt) {
    int nid = ids[gl][tt * 16 + r];
    const f32x4* px = (const f32x4*)(x + (size_t)nid * 128 + p * 32 + g * 8);
    f32x4 a = px[0], b = px[1];
    half8 hx;
#pragma unroll
    for (int e = 0; e < 4; ++e) {
      hx[e] = (_Float16)a[e];
      hx[4 + e] = (_Float16)b[e];
    }
    *(half8*)(xg + tt * 4096 + xwb) = hx;
  }
  f32x4 h = (f32x4){0.f, 0.f, 0.f, 0.f};
  __syncthreads();

  f32x4 eP0, eP1, oP0, oP1;  // gather prefetch sets (even/odd steps)

#define GRU_STEP(T_, ISS0, ISS1, CV0, CV1)                                     \
  {                                                                            \
    int nid2 = ids[gl][(((T_) + 2) & 15) * 16 + r];                            \
    const f32x4* px = (const f32x4*)(x + (size_t)nid2 * 128 + p * 32 + g * 8); \
    ISS0 = px[0];                                                              \
    ISS1 = px[1];                                                              \
    const int RB = (T_) & 1;                                                   \
    char* xb = xg + RB * 4096;                                                 \
    char* rbh = hg + RB * 2048;                                                \
    char* wbh = hg + (RB ^ 1) * 2048;                                          \
    half8 Ax0 = *(const half8*)(xb + r * 256 + ((g * 16) ^ swz));              \
    half8 Ax1 = *(const half8*)(xb + r * 256 + ((64 + g * 16) ^ swz));         \
    half8 Ax2 = *(const half8*)(xb + r * 256 + ((128 + g * 16) ^ swz));        \
    half8 Ax3 = *(const half8*)(xb + r * 256 + ((192 + g * 16) ^ swz));        \
    half8 Ah0 = *(const half8*)(rbh + ((r * 128 + g * 16) ^ swz));             \
    half8 Ah1 = *(const half8*)(rbh + ((r * 128 + 64 + g * 16) ^ swz));        \
    f32x4 aR = (f32x4){br_, br_, br_, br_};                                    \
    f32x4 aZ = (f32x4){bz_, bz_, bz_, bz_};                                    \
    f32x4 aN = (f32x4){bin_, bin_, bin_, bin_};                                \
    f32x4 aH = (f32x4){bhn_, bhn_, bhn_, bhn_};                                \
    aR = MFMA_F16(Ax0, Bi[0][0], aR);                                          \
    aR = MFMA_F16(Ax1, Bi[0][1], aR);                                          \
    aR = MFMA_F16(Ax2, Bi[0][2], aR);                                          \
    aR = MFMA_F16(Ax3, Bi[0][3], aR);                                          \
    aZ = MFMA_F16(Ax0, Bi[1][0], aZ);                                          \
    aZ = MFMA_F16(Ax1, Bi[1][1], aZ);                                          \
    aZ = MFMA_F16(Ax2, Bi[1][2], aZ);                                          \
    aZ = MFMA_F16(Ax3, Bi[1][3], aZ);                                          \
    aN = MFMA_F16(Ax0, Bi[2][0], aN);                                          \
    aN = MFMA_F16(Ax1, Bi[2][1], aN);                                          \
    aN = MFMA_F16(Ax2, Bi[2][2], aN);                                          \
    aN = MFMA_F16(Ax3, Bi[2][3], aN);                                          \
    aR = MFMA_F16(Ah0, Bh[0][0], aR);                                          \
    aR = MFMA_F16(Ah1, Bh[0][1], aR);                                          \
    aZ = MFMA_F16(Ah0, Bh[1][0], aZ);                                          \
    aZ = MFMA_F16(Ah1, Bh[1][1], aZ);                                          \
    aH = MFMA_F16(Ah0, Bh[2][0], aH);                                          \
    aH = MFMA_F16(Ah1, Bh[2][1], aH);                                          \
    _Pragma("unroll") for (int rr = 0; rr < 4; ++rr) {                         \
      float rg = __builtin_amdgcn_rcpf(1.f + __expf(-aR[rr]));                 \
      float zg = __builtin_amdgcn_rcpf(1.f + __expf(-aZ[rr]));                 \
      float pn = aN[rr] + rg * aH[rr];                                         \
      float e2 = __expf(2.f * pn);                                             \
      float nn = 1.f - 2.f * __builtin_amdgcn_rcpf(e2 + 1.f);                  \
      h[rr] = (1.f - zg) * nn + zg * h[rr];                                    \
    }                                                                          \
    if ((T_) < 15) {                                                           \
      _Pragma("unroll") for (int rr = 0; rr < 4; ++rr) {                       \
        int row = g * 4 + rr;                                                  \
        int byte = (row * 128 + j0 * 2) ^ ((row & 7) << 4);                    \
        *(_Float16*)(wbh + byte) = (_Float16)h[rr];                            \
      }                                                                        \
    }                                                                          \
    if ((T_) >= 1 && (T_) < 15) { /* convert arrived set -> stage xs[t+1] */   \
      half8 hx;                                                                \
      _Pragma("unroll") for (int e = 0; e < 4; ++e) {                          \
        hx[e] = (_Float16)CV0[e];                                              \
        hx[4 + e] = (_Float16)CV1[e];                                          \
      }                                                                        \
      *(half8*)(xg + (((T_) + 1) & 1) * 4096 + xwb) = hx;                      \
    }                                                                          \
    asm volatile("s_waitcnt lgkmcnt(0)" ::: "memory");                         \
    __builtin_amdgcn_s_barrier();                                              \
    __builtin_amdgcn_sched_barrier(0);                                         \
  }

  for (int t = 0; t < 16; t += 2) {
    GRU_STEP(t, eP0, eP1, oP0, oP1);
    GRU_STEP(t + 1, oP0, oP1, eP0, eP1);
  }
#undef GRU_STEP

  {
    float s = h[0] + h[1] + h[2] + h[3];
    s += __shfl_xor(s, 16);
    s += __shfl_xor(s, 32);
    if (g == 0) genc[gph * 64 + j0] = s * 0.0625f;
  }
}

// ---------------- Kernel 2: fused BN stats + BN apply + MLP + log_softmax ----------------
__global__ __launch_bounds__(256) void k_post(const float* __restrict__ genc,
                                              const float* __restrict__ gamma,
                                              const float* __restrict__ beta,
                                              const float* __restrict__ W1,
                                              const float* __restrict__ b1,
                                              const float* __restrict__ W2,
                                              const float* __restrict__ b2,
                                              float* __restrict__ out) {
  __shared__ float sum_s[4][64], sq_s[4][64], sc[64], sh[64];
  __shared__ float w1[32 * 64], w2[10 * 32], bb1[32], bb2[10];
  const int tid = threadIdx.x;
  const int j = tid & 63, grp = tid >> 6;

  float s = 0.f, q = 0.f;
  for (int rr = 0; rr < 256; ++rr) {
    float v = genc[(grp * 256 + rr) * 64 + j];
    s += v;
    q += v * v;
  }
  sum_s[grp][j] = s;
  sq_s[grp][j] = q;

  for (int i = tid; i < 32 * 64; i += 256) w1[i] = W1[i];
  for (int i = tid; i < 10 * 32; i += 256) w2[i] = W2[i];
  if (tid < 32) bb1[tid] = b1[tid];
  if (tid >= 32 && tid < 42) bb2[tid - 32] = b2[tid - 32];
  __syncthreads();

  if (grp == 0) {
    float S = sum_s[0][j] + sum_s[1][j] + sum_s[2][j] + sum_s[3][j];
    float Q = sq_s[0][j] + sq_s[1][j] + sq_s[2][j] + sq_s[3][j];
    float mean = S * (1.f / 1024.f);
    float var = Q * (1.f / 1024.f) - mean * mean;
    float rstd = rsqrtf(var + 1e-5f);
    float scv = gamma[j] * rstd;
    sc[j] = scv;
    sh[j] = beta[j] - mean * scv;
  }
  __syncthreads();

  const int row = blockIdx.x * 256 + tid;
  float gn[64];
  const f32x4* gp = (const f32x4*)(genc + row * 64);
#pragma unroll
  for (int jq = 0; jq < 16; ++jq) {
    f32x4 v = gp[jq];
#pragma unroll
    for (int e = 0; e < 4; ++e) gn[jq * 4 + e] = v[e] * sc[jq * 4 + e] + sh[jq * 4 + e];
  }

  float h1[32];
#pragma unroll
  for (int i = 0; i < 32; ++i) {
    float a = bb1[i];
#pragma unroll
    for (int jj = 0; jj < 64; ++jj) a += w1[i * 64 + jj] * gn[jj];
    h1[i] = fmaxf(a, 0.f);
  }

  float lg[10];
  float mx = -1e30f;
#pragma unroll
  for (int c = 0; c < 10; ++c) {
    float a = bb2[c];
#pragma unroll
    for (int i = 0; i < 32; ++i) a += w2[c * 32 + i] * h1[i];
    lg[c] = a;
    mx = fmaxf(mx, a);
  }
  float se = 0.f;
#pragma unroll
  for (int c = 0; c < 10; ++c) se += __expf(lg[c] - mx);
  float lse = mx + __logf(se);
#pragma unroll
  for (int c = 0; c < 10; ++c) out[row * 10 + c] = lg[c] - lse;
}

// ---------------- host launcher ----------------
extern "C" void kernel_launch(void* const* d_in, const int* in_sizes, int n_in,
                              void* d_out, int out_size, void* d_ws, size_t ws_size,
                              hipStream_t stream) {
  const float* x = (const float*)d_in[0];
  const int* walks = (const int*)d_in[1];
  const float* Wenc = (const float*)d_in[3];
  const float* benc = (const float*)d_in[4];
  const float* Wih = (const float*)d_in[5];
  const float* Whh = (const float*)d_in[6];
  const float* bih = (const float*)d_in[7];
  const float* bhh = (const float*)d_in[8];
  const float* gamma = (const float*)d_in[9];
  const float* beta = (const float*)d_in[10];
  const float* W1 = (const float*)d_in[11];
  const float* b1 = (const float*)d_in[12];
  const float* W2 = (const float*)d_in[13];
  const float* b2 = (const float*)d_in[14];
  float* out = (float*)d_out;

  char* ws = (char*)d_ws;
  _Float16* wgi = (_Float16*)ws;            // 49152 B
  _Float16* whhp = (_Float16*)(ws + 49152); // 24576 B
  float* bcb = (float*)(ws + 73728);        // 768 B
  float* genc = (float*)(ws + 74752);       // 262144 B

  // R16: encoder folded into GRU via combined weights (gi = x @ (Wih*Wenc)^T).
  k_prep<<<dim3(24), dim3(256), 0, stream>>>(Wenc, benc, Wih, Whh, bih, wgi, whhp, bcb);
  k_gru<<<dim3(512), dim3(512), 0, stream>>>(x, walks, wgi, whhp, bcb, bhh, genc);
  k_post<<<dim3(4), dim3(256), 0, stream>>>(genc, gamma, beta, W1, b1, W2, b2, out);
}

// Round 17
// 82.037 us; speedup vs baseline: 1.7228x; 1.7228x over previous
//
#include <hip/hip_runtime.h>
#include <stdint.h>

typedef _Float16 half8 __attribute__((ext_vector_type(8)));
typedef _Float16 half4 __attribute__((ext_vector_type(4)));
typedef float f32x4 __attribute__((ext_vector_type(4)));

#define MFMA_F16(A, B, C) __builtin_amdgcn_mfma_f32_16x16x32_f16(A, B, C, 0, 0, 0)

#define NN 200000
#define NT 3125     // 200000 / 64 exactly
#define GSTRIDE 768 // k_enc grid (3 blocks/CU)

// ---------------- Kernel 1: encoder — REG-STAGED pipeline, 3 blocks/CU ----------------
// Loads go global->VGPR (m13-proven 6.3TB/s path), park into single 32KB LDS
// buffer (wave-private rows -> no in-loop barriers). 48KB LDS total -> 3
// blocks/CU = 12 waves/CU (1.5x the gload_lds version's occupancy).
__global__ __launch_bounds__(256, 3) void k_enc(const float* __restrict__ x,
                                                const float* __restrict__ Wenc,
                                                const float* __restrict__ benc,
                                                _Float16* __restrict__ xenc) {
  __shared__ float xl[64 * 128];          // 32 KB x tile, col-swizzled rows
  __shared__ _Float16 wlds[16 * 64 * 8];  // 16 KB frag-packed fp16 Wenc

  const int tid = threadIdx.x;
  const int lane = tid & 63, wv = tid >> 6;
  const int r = lane & 15, g = lane >> 4;
  const int lrh = lane >> 5;  // row parity this lane feeds
  const int cg = lane & 31;   // col granule (16B units)

  const int t0 = blockIdx.x;

  // issue tile t0's loads into regs
  f32x4 xin[8];
#pragma unroll
  for (int i = 0; i < 8; ++i) {
    int grow = t0 * 64 + wv * 16 + 2 * i + lrh;
    if (grow >= NN) grow = NN - 1;
    xin[i] = *(const f32x4*)((const char*)(x + (size_t)grow * 128) + cg * 16);
  }

  // stage Wenc -> frag-packed fp16 LDS (overlaps x loads)
  for (int i4 = tid; i4 < 2048; i4 += 256) {
    int idx = i4 * 4;
    f32x4 v = *(const f32x4*)(Wenc + idx);
    int j = idx >> 7, k = idx & 127;
    int tile = (j >> 4) * 4 + (k >> 5);
    int ln = ((k >> 3) & 3) * 16 + (j & 15);
    half4 h;
    h[0] = (_Float16)v[0]; h[1] = (_Float16)v[1];
    h[2] = (_Float16)v[2]; h[3] = (_Float16)v[3];
    *(half4*)&wlds[(tile * 64 + ln) * 8 + (k & 7)] = h;
  }

  // park tile t0 (swizzled on the write side)
#pragma unroll
  for (int i = 0; i < 8; ++i) {
    int row = wv * 16 + 2 * i + lrh;
    *(f32x4*)((char*)xl + row * 512 + ((cg * 16) ^ ((row & 7) << 4))) = xin[i];
  }
  __syncthreads();  // wlds ready (xl rows are wave-private)

  half8 W[4][4];
#pragma unroll
  for (int jt = 0; jt < 4; ++jt)
#pragma unroll
    for (int kt = 0; kt < 4; ++kt)
      W[jt][kt] = *(const half8*)&wlds[((jt * 4 + kt) * 64 + lane) * 8];

  float bb[4][4];
#pragma unroll
  for (int jt = 0; jt < 4; ++jt)
#pragma unroll
    for (int rr = 0; rr < 4; ++rr) bb[jt][rr] = benc[jt * 16 + g * 4 + rr];

  const int sw = (r & 7) << 4;

  for (int t = t0; t < NT; t += GSTRIDE) {
    int tn = t + GSTRIDE;
    if (tn < NT) {
      // issue next tile's loads (in flight across current tile's compute)
#pragma unroll
      for (int i = 0; i < 8; ++i) {
        int grow = tn * 64 + wv * 16 + 2 * i + lrh;
        if (grow >= NN) grow = NN - 1;
        xin[i] = *(const f32x4*)((const char*)(x + (size_t)grow * 128) + cg * 16);
      }
    }

    // compute tile t from this wave's LDS rows
    const char* rp = (const char*)xl + (wv * 16 + r) * 512;
    f32x4 acc[4];
#pragma unroll
    for (int jt = 0; jt < 4; ++jt)
      acc[jt] = (f32x4){bb[jt][0], bb[jt][1], bb[jt][2], bb[jt][3]};

#pragma unroll
    for (int kt = 0; kt < 4; ++kt) {
      f32x4 v0 = *(const f32x4*)(rp + ((kt * 128 + g * 32) ^ sw));
      f32x4 v1 = *(const f32x4*)(rp + ((kt * 128 + g * 32 + 16) ^ sw));
      half8 a;
#pragma unroll
      for (int e = 0; e < 4; ++e) {
        a[e] = (_Float16)v0[e];
        a[4 + e] = (_Float16)v1[e];
      }
#pragma unroll
      for (int jt = 0; jt < 4; ++jt)
        acc[jt] = MFMA_F16(W[jt][kt], a, acc[jt]);  // D=[hid][node]
    }

    int node = t * 64 + wv * 16 + r;
    if (node < NN) {
#pragma unroll
      for (int jt = 0; jt < 4; ++jt) {
        half4 o;
        o[0] = (_Float16)acc[jt][0]; o[1] = (_Float16)acc[jt][1];
        o[2] = (_Float16)acc[jt][2]; o[3] = (_Float16)acc[jt][3];
        *(half4*)&xenc[(size_t)node * 64 + jt * 16 + g * 4] = o;
      }
    }

    if (tn < NT) {
      // park t+1 into own rows (per-wave in-order LDS -> no barrier)
#pragma unroll
      for (int i = 0; i < 8; ++i) {
        int row = wv * 16 + 2 * i + lrh;
        *(f32x4*)((char*)xl + row * 512 + ((cg * 16) ^ ((row & 7) << 4))) = xin[i];
      }
    }
  }
}

// ---------------- Kernel 2: GRU v3 (R15 bytes; measured ~23-28us) ----------------
__global__ __launch_bounds__(512, 4) void k_gru(const _Float16* __restrict__ xenc,
                                                const int* __restrict__ walks,
                                                const float* __restrict__ Wih,
                                                const float* __restrict__ Whh,
                                                const float* __restrict__ bih,
                                                const float* __restrict__ bhh,
                                                float* __restrict__ genc) {
  __shared__ _Float16 wih_lds[24 * 64 * 8];  // 24 KB frag-packed W_ih
  __shared__ _Float16 whh_lds[24 * 64 * 8];  // 24 KB frag-packed W_hh
  __shared__ _Float16 h_lds[2][2][16 * 64];  // [graph][buf]
  __shared__ int ids[2][256];

  const int tid = threadIdx.x;
  const int lane = tid & 63, wv = tid >> 6;
  const int r = lane & 15, g = lane >> 4;
  const int p = wv & 3;    // 16-col quarter this wave owns
  const int gl = wv >> 2;  // local graph 0/1
  const int gph = blockIdx.x * 2 + gl;

  for (int idx = tid; idx < 192 * 64; idx += 512) {
    int j = idx >> 6, k = idx & 63;
    int tile = (j >> 4) * 2 + (k >> 5);
    int ln = ((k >> 3) & 3) * 16 + (j & 15);
    int off = (tile * 64 + ln) * 8 + (k & 7);
    wih_lds[off] = (_Float16)Wih[idx];
    whh_lds[off] = (_Float16)Whh[idx];
  }

  if ((wv & 3) == 0) {
    const int* wp = walks + gph * 256;
    int4 v = *(const int4*)(wp + lane * 4);
    int vals[4] = {v.x, v.y, v.z, v.w};
#pragma unroll
    for (int i = 0; i < 4; ++i) {
      int m = lane * 4 + i;  // m = w*16 + t
      ids[gl][(m & 15) * 16 + (m >> 4)] = vals[i];
    }
  }

  for (int i = tid; i < 4096; i += 512) ((_Float16*)h_lds)[i] = (_Float16)0.f;

  __syncthreads();

  half8 Bi[3][2], Bh[3][2];
#pragma unroll
  for (int G = 0; G < 3; ++G)
#pragma unroll
    for (int kt = 0; kt < 2; ++kt) {
      int T = G * 4 + p;
      Bi[G][kt] = *(const half8*)&wih_lds[((T * 2 + kt) * 64 + lane) * 8];
      Bh[G][kt] = *(const half8*)&whh_lds[((T * 2 + kt) * 64 + lane) * 8];
    }

  const int j0 = p * 16 + r;
  const float br_ = bih[j0] + bhh[j0];
  const float bz_ = bih[64 + j0] + bhh[64 + j0];
  const float bin_ = bih[128 + j0];
  const float bhn_ = bhh[128 + j0];

  f32x4 h = (f32x4){0.f, 0.f, 0.f, 0.f};
  const int swz = (r & 7) << 4;

  half8 AxA0, AxA1, AxB0, AxB1;
  {
    int n0 = ids[gl][0 * 16 + r];
    const _Float16* p0 = xenc + (size_t)n0 * 64 + g * 8;
    AxA0 = *(const half8*)p0;
    AxA1 = *(const half8*)(p0 + 32);
    int n1 = ids[gl][1 * 16 + r];
    const _Float16* p1 = xenc + (size_t)n1 * 64 + g * 8;
    AxB0 = *(const half8*)p1;
    AxB1 = *(const half8*)(p1 + 32);
  }

#define GRU_STEP(T_, RB, AX0, AX1)                                             \
  {                                                                            \
    int nid = ids[gl][(((T_) + 2) & 15) * 16 + r];                             \
    const _Float16* xp = xenc + (size_t)nid * 64 + g * 8;                      \
    half8 NX0 = *(const half8*)xp;                                             \
    half8 NX1 = *(const half8*)(xp + 32);                                      \
    char* rbase = (char*)&h_lds[gl][RB][0];                                    \
    char* wbase = (char*)&h_lds[gl][RB ^ 1][0];                                \
    half8 Ah0 = *(const half8*)(rbase + ((r * 128 + g * 16) ^ swz));           \
    half8 Ah1 = *(const half8*)(rbase + ((r * 128 + 64 + g * 16) ^ swz));      \
    f32x4 aR = (f32x4){br_, br_, br_, br_};                                    \
    f32x4 aZ = (f32x4){bz_, bz_, bz_, bz_};                                    \
    f32x4 aN = (f32x4){bin_, bin_, bin_, bin_};                                \
    f32x4 aH = (f32x4){bhn_, bhn_, bhn_, bhn_};                                \
    aR = MFMA_F16(AX0, Bi[0][0], aR);                                          \
    aR = MFMA_F16(AX1, Bi[0][1], aR);                                          \
    aZ = MFMA_F16(AX0, Bi[1][0], aZ);                                          \
    aZ = MFMA_F16(AX1, Bi[1][1], aZ);                                          \
    aN = MFMA_F16(AX0, Bi[2][0], aN);                                          \
    aN = MFMA_F16(AX1, Bi[2][1], aN);                                          \
    aR = MFMA_F16(Ah0, Bh[0][0], aR);                                          \
    aR = MFMA_F16(Ah1, Bh[0][1], aR);                                          \
    aZ = MFMA_F16(Ah0, Bh[1][0], aZ);                                          \
    aZ = MFMA_F16(Ah1, Bh[1][1], aZ);                                          \
    aH = MFMA_F16(Ah0, Bh[2][0], aH);                                          \
    aH = MFMA_F16(Ah1, Bh[2][1], aH);                                          \
    _Pragma("unroll") for (int rr = 0; rr < 4; ++rr) {                         \
      float rg = __builtin_amdgcn_rcpf(1.f + __expf(-aR[rr]));                 \
      float zg = __builtin_amdgcn_rcpf(1.f + __expf(-aZ[rr]));                 \
      float pn = aN[rr] + rg * aH[rr];                                         \
      float e2 = __expf(2.f * pn);                                             \
      float nn = 1.f - 2.f * __builtin_amdgcn_rcpf(e2 + 1.f);                  \
      h[rr] = (1.f - zg) * nn + zg * h[rr];                                    \
    }                                                                          \
    if ((T_) < 15) {                                                           \
      _Pragma("unroll") for (int rr = 0; rr < 4; ++rr) {                       \
        int row = g * 4 + rr;                                                  \
        int byte = (row * 128 + j0 * 2) ^ ((row & 7) << 4);                    \
        *(_Float16*)(wbase + byte) = (_Float16)h[rr];                          \
      }                                                                        \
    }                                                                          \
    asm volatile("s_waitcnt lgkmcnt(0)" ::: "memory");                         \
    __builtin_amdgcn_s_barrier();                                              \
    __builtin_amdgcn_sched_barrier(0);                                         \
    AX0 = NX0;                                                                 \
    AX1 = NX1;                                                                 \
  }

  for (int t = 0; t < 16; t += 2) {
    GRU_STEP(t, 0, AxA0, AxA1);
    GRU_STEP(t + 1, 1, AxB0, AxB1);
  }
#undef GRU_STEP

  {
    float s = h[0] + h[1] + h[2] + h[3];
    s += __shfl_xor(s, 16);
    s += __shfl_xor(s, 32);
    if (g == 0) genc[gph * 64 + j0] = s * 0.0625f;
  }
}

// ---------------- Kernel 3: fused BN stats + BN apply + MLP + log_softmax ----------------
__global__ __launch_bounds__(256) void k_post(const float* __restrict__ genc,
                                              const float* __restrict__ gamma,
                                              const float* __restrict__ beta,
                                              const float* __restrict__ W1,
                                              const float* __restrict__ b1,
                                              const float* __restrict__ W2,
                                              const float* __restrict__ b2,
                                              float* __restrict__ out) {
  __shared__ float sum_s[4][64], sq_s[4][64], sc[64], sh[64];
  __shared__ float w1[32 * 64], w2[10 * 32], bb1[32], bb2[10];
  const int tid = threadIdx.x;
  const int j = tid & 63, grp = tid >> 6;

  float s = 0.f, q = 0.f;
  for (int rr = 0; rr < 256; ++rr) {
    float v = genc[(grp * 256 + rr) * 64 + j];
    s += v;
    q += v * v;
  }
  sum_s[grp][j] = s;
  sq_s[grp][j] = q;

  for (int i = tid; i < 32 * 64; i += 256) w1[i] = W1[i];
  for (int i = tid; i < 10 * 32; i += 256) w2[i] = W2[i];
  if (tid < 32) bb1[tid] = b1[tid];
  if (tid >= 32 && tid < 42) bb2[tid - 32] = b2[tid - 32];
  __syncthreads();

  if (grp == 0) {
    float S = sum_s[0][j] + sum_s[1][j] + sum_s[2][j] + sum_s[3][j];
    float Q = sq_s[0][j] + sq_s[1][j] + sq_s[2][j] + sq_s[3][j];
    float mean = S * (1.f / 1024.f);
    float var = Q * (1.f / 1024.f) - mean * mean;
    float rstd = rsqrtf(var + 1e-5f);
    float scv = gamma[j] * rstd;
    sc[j] = scv;
    sh[j] = beta[j] - mean * scv;
  }
  __syncthreads();

  const int row = blockIdx.x * 256 + tid;
  float gn[64];
  const f32x4* gp = (const f32x4*)(genc + row * 64);
#pragma unroll
  for (int jq = 0; jq < 16; ++jq) {
    f32x4 v = gp[jq];
#pragma unroll
    for (int e = 0; e < 4; ++e) gn[jq * 4 + e] = v[e] * sc[jq * 4 + e] + sh[jq * 4 + e];
  }

  float h1[32];
#pragma unroll
  for (int i = 0; i < 32; ++i) {
    float a = bb1[i];
#pragma unroll
    for (int jj = 0; jj < 64; ++jj) a += w1[i * 64 + jj] * gn[jj];
    h1[i] = fmaxf(a, 0.f);
  }

  float lg[10];
  float mx = -1e30f;
#pragma unroll
  for (int c = 0; c < 10; ++c) {
    float a = bb2[c];
#pragma unroll
    for (int i = 0; i < 32; ++i) a += w2[c * 32 + i] * h1[i];
    lg[c] = a;
    mx = fmaxf(mx, a);
  }
  float se = 0.f;
#pragma unroll
  for (int c = 0; c < 10; ++c) se += __expf(lg[c] - mx);
  float lse = mx + __logf(se);
#pragma unroll
  for (int c = 0; c < 10; ++c) out[row * 10 + c] = lg[c] - lse;
}

// ---------------- host launcher ----------------
extern "C" void kernel_launch(void* const* d_in, const int* in_sizes, int n_in,
                              void* d_out, int out_size, void* d_ws, size_t ws_size,
                              hipStream_t stream) {
  const float* x = (const float*)d_in[0];
  const int* walks = (const int*)d_in[1];
  const float* Wenc = (const float*)d_in[3];
  const float* benc = (const float*)d_in[4];
  const float* Wih = (const float*)d_in[5];
  const float* Whh = (const float*)d_in[6];
  const float* bih = (const float*)d_in[7];
  const float* bhh = (const float*)d_in[8];
  const float* gamma = (const float*)d_in[9];
  const float* beta = (const float*)d_in[10];
  const float* W1 = (const float*)d_in[11];
  const float* b1 = (const float*)d_in[12];
  const float* W2 = (const float*)d_in[13];
  const float* b2 = (const float*)d_in[14];
  float* out = (float*)d_out;

  char* ws = (char*)d_ws;
  _Float16* xenc = (_Float16*)ws;         // 25,600,000 B
  float* genc = (float*)(ws + 25600000);  // 262,144 B

  // R17: R15 baseline + reg-staged enc at 3 blocks/CU (single attributable change).
  k_enc<<<dim3(GSTRIDE), dim3(256), 0, stream>>>(x, Wenc, benc, xenc);
  k_gru<<<dim3(512), dim3(512), 0, stream>>>(xenc, walks, Wih, Whh, bih, bhh, genc);
  k_post<<<dim3(4), dim3(256), 0, stream>>>(genc, gamma, beta, W1, b1, W2, b2, out);
}

// Round 18
// 80.399 us; speedup vs baseline: 1.7579x; 1.0204x over previous
//
#include <hip/hip_runtime.h>
#include <stdint.h>

typedef _Float16 half8 __attribute__((ext_vector_type(8)));
typedef _Float16 half4 __attribute__((ext_vector_type(4)));
typedef float f32x4 __attribute__((ext_vector_type(4)));

#define MFMA_F16(A, B, C) __builtin_amdgcn_mfma_f32_16x16x32_f16(A, B, C, 0, 0, 0)

#define NN 200000
#define NT 3125     // 200000 / 64 exactly
#define GSTRIDE 512 // k_enc grid

__device__ __forceinline__ void gload_lds16(const void* gp, void* lp) {
  __builtin_amdgcn_global_load_lds(
      (const __attribute__((address_space(1))) uint32_t*)(gp),
      (__attribute__((address_space(3))) uint32_t*)(lp), 16, 0, 0);
}

// ---------------- Kernel 1: encoder (R15 bytes — closed at ~33us cold) ----------------
__global__ __launch_bounds__(256, 2) void k_enc(const float* __restrict__ x,
                                                const float* __restrict__ Wenc,
                                                const float* __restrict__ benc,
                                                _Float16* __restrict__ xenc) {
  __shared__ float xl[2][64 * 128];       // 2 x 32 KB, col-swizzled rows
  __shared__ _Float16 wlds[16 * 64 * 8];  // 16 KB frag-packed fp16 Wenc

  const int tid = threadIdx.x;
  const int lane = tid & 63, wv = tid >> 6;
  const int r = lane & 15, g = lane >> 4;
  const int t0 = blockIdx.x;

#define ISSUE8(TT, BUF)                                                        \
  {                                                                            \
    _Pragma("unroll") for (int i = 0; i < 8; ++i) {                            \
      int row = wv * 16 + 2 * i + (lane >> 5);                                 \
      int grow = (TT) * 64 + row;                                              \
      if (grow >= NN) grow = NN - 1;                                           \
      int scol = ((lane & 31) * 16) ^ ((row & 7) << 4);                        \
      gload_lds16((const char*)(x + (size_t)grow * 128) + scol,                \
                  (char*)&xl[BUF][0] + (wv * 16 + 2 * i) * 512);               \
    }                                                                          \
  }

  ISSUE8(t0, 0);
  for (int i4 = tid; i4 < 2048; i4 += 256) {
    int idx = i4 * 4;
    f32x4 v = *(const f32x4*)(Wenc + idx);
    int j = idx >> 7, k = idx & 127;
    int tile = (j >> 4) * 4 + (k >> 5);
    int ln = ((k >> 3) & 3) * 16 + (j & 15);
    half4 h;
    h[0] = (_Float16)v[0]; h[1] = (_Float16)v[1];
    h[2] = (_Float16)v[2]; h[3] = (_Float16)v[3];
    *(half4*)&wlds[(tile * 64 + ln) * 8 + (k & 7)] = h;
  }
  __syncthreads();

  half8 W[4][4];
#pragma unroll
  for (int jt = 0; jt < 4; ++jt)
#pragma unroll
    for (int kt = 0; kt < 4; ++kt)
      W[jt][kt] = *(const half8*)&wlds[((jt * 4 + kt) * 64 + lane) * 8];

  float bb[4][4];
#pragma unroll
  for (int jt = 0; jt < 4; ++jt)
#pragma unroll
    for (int rr = 0; rr < 4; ++rr) bb[jt][rr] = benc[jt * 16 + g * 4 + rr];

  const int sw = (r & 7) << 4;
  int buf = 0;

  for (int t = t0; t < NT; t += GSTRIDE) {
    int tn = t + GSTRIDE;
    if (tn < NT) {
      ISSUE8(tn, buf ^ 1);
      asm volatile("s_waitcnt vmcnt(8)" ::: "memory");
    } else {
      asm volatile("s_waitcnt vmcnt(0)" ::: "memory");
    }
    __builtin_amdgcn_sched_barrier(0);

    const char* rp = (const char*)&xl[buf][0] + (wv * 16 + r) * 512;
    f32x4 acc[4];
#pragma unroll
    for (int jt = 0; jt < 4; ++jt)
      acc[jt] = (f32x4){bb[jt][0], bb[jt][1], bb[jt][2], bb[jt][3]};

#pragma unroll
    for (int kt = 0; kt < 4; ++kt) {
      f32x4 v0 = *(const f32x4*)(rp + ((kt * 128 + g * 32) ^ sw));
      f32x4 v1 = *(const f32x4*)(rp + ((kt * 128 + g * 32 + 16) ^ sw));
      half8 a;
#pragma unroll
      for (int e = 0; e < 4; ++e) {
        a[e] = (_Float16)v0[e];
        a[4 + e] = (_Float16)v1[e];
      }
#pragma unroll
      for (int jt = 0; jt < 4; ++jt)
        acc[jt] = MFMA_F16(W[jt][kt], a, acc[jt]);  // D=[hid][node]
    }

    int node = t * 64 + wv * 16 + r;
    if (node < NN) {
#pragma unroll
      for (int jt = 0; jt < 4; ++jt) {
        half4 o;
        o[0] = (_Float16)acc[jt][0]; o[1] = (_Float16)acc[jt][1];
        o[2] = (_Float16)acc[jt][2]; o[3] = (_Float16)acc[jt][3];
        *(half4*)&xenc[(size_t)node * 64 + jt * 16 + g * 4] = o;
      }
    }
    buf ^= 1;
  }
#undef ISSUE8
}

// ---------------- Kernel 2: GRU v6 — v3 + exp2-prescaled weights ----------------
// r/z-gate rows of Wih/Whh (+biases) pre-scaled by -log2(e); n-gate rows by
// +2*log2(e), folded into the fp16 LDS staging. Gate math becomes
// rcp(1+exp2(acc)) / exp2(pn) directly — ~25% fewer VALU ops per step.
__global__ __launch_bounds__(512, 4) void k_gru(const _Float16* __restrict__ xenc,
                                                const int* __restrict__ walks,
                                                const float* __restrict__ Wih,
                                                const float* __restrict__ Whh,
                                                const float* __restrict__ bih,
                                                const float* __restrict__ bhh,
                                                float* __restrict__ genc) {
  __shared__ _Float16 wih_lds[24 * 64 * 8];  // 24 KB frag-packed, PRESCALED
  __shared__ _Float16 whh_lds[24 * 64 * 8];  // 24 KB frag-packed, PRESCALED
  __shared__ _Float16 h_lds[2][2][16 * 64];  // [graph][buf]
  __shared__ int ids[2][256];

  const int tid = threadIdx.x;
  const int lane = tid & 63, wv = tid >> 6;
  const int r = lane & 15, g = lane >> 4;
  const int p = wv & 3;    // 16-col quarter this wave owns
  const int gl = wv >> 2;  // local graph 0/1
  const int gph = blockIdx.x * 2 + gl;

  const float NL2E = -1.4426950408889634f;  // -log2(e)
  const float TL2E = 2.8853900817779268f;   // 2*log2(e)

  for (int idx = tid; idx < 192 * 64; idx += 512) {
    int j = idx >> 6, k = idx & 63;
    int tile = (j >> 4) * 2 + (k >> 5);
    int ln = ((k >> 3) & 3) * 16 + (j & 15);
    int off = (tile * 64 + ln) * 8 + (k & 7);
    float sc = (j < 128) ? NL2E : TL2E;
    wih_lds[off] = (_Float16)(Wih[idx] * sc);
    whh_lds[off] = (_Float16)(Whh[idx] * sc);
  }

  if ((wv & 3) == 0) {
    const int* wp = walks + gph * 256;
    int4 v = *(const int4*)(wp + lane * 4);
    int vals[4] = {v.x, v.y, v.z, v.w};
#pragma unroll
    for (int i = 0; i < 4; ++i) {
      int m = lane * 4 + i;  // m = w*16 + t
      ids[gl][(m & 15) * 16 + (m >> 4)] = vals[i];
    }
  }

  for (int i = tid; i < 4096; i += 512) ((_Float16*)h_lds)[i] = (_Float16)0.f;

  __syncthreads();

  half8 Bi[3][2], Bh[3][2];
#pragma unroll
  for (int G = 0; G < 3; ++G)
#pragma unroll
    for (int kt = 0; kt < 2; ++kt) {
      int T = G * 4 + p;
      Bi[G][kt] = *(const half8*)&wih_lds[((T * 2 + kt) * 64 + lane) * 8];
      Bh[G][kt] = *(const half8*)&whh_lds[((T * 2 + kt) * 64 + lane) * 8];
    }

  const int j0 = p * 16 + r;
  const float br_ = (bih[j0] + bhh[j0]) * NL2E;
  const float bz_ = (bih[64 + j0] + bhh[64 + j0]) * NL2E;
  const float bin_ = bih[128 + j0] * TL2E;
  const float bhn_ = bhh[128 + j0] * TL2E;

  f32x4 h = (f32x4){0.f, 0.f, 0.f, 0.f};
  const int swz = (r & 7) << 4;

  half8 AxA0, AxA1, AxB0, AxB1;
  {
    int n0 = ids[gl][0 * 16 + r];
    const _Float16* p0 = xenc + (size_t)n0 * 64 + g * 8;
    AxA0 = *(const half8*)p0;
    AxA1 = *(const half8*)(p0 + 32);
    int n1 = ids[gl][1 * 16 + r];
    const _Float16* p1 = xenc + (size_t)n1 * 64 + g * 8;
    AxB0 = *(const half8*)p1;
    AxB1 = *(const half8*)(p1 + 32);
  }

#define GRU_STEP(T_, RB, AX0, AX1)                                             \
  {                                                                            \
    int nid = ids[gl][(((T_) + 2) & 15) * 16 + r];                             \
    const _Float16* xp = xenc + (size_t)nid * 64 + g * 8;                      \
    half8 NX0 = *(const half8*)xp;                                             \
    half8 NX1 = *(const half8*)(xp + 32);                                      \
    char* rbase = (char*)&h_lds[gl][RB][0];                                    \
    char* wbase = (char*)&h_lds[gl][RB ^ 1][0];                                \
    half8 Ah0 = *(const half8*)(rbase + ((r * 128 + g * 16) ^ swz));           \
    half8 Ah1 = *(const half8*)(rbase + ((r * 128 + 64 + g * 16) ^ swz));      \
    f32x4 aR = (f32x4){br_, br_, br_, br_};                                    \
    f32x4 aZ = (f32x4){bz_, bz_, bz_, bz_};                                    \
    f32x4 aN = (f32x4){bin_, bin_, bin_, bin_};                                \
    f32x4 aH = (f32x4){bhn_, bhn_, bhn_, bhn_};                                \
    aR = MFMA_F16(AX0, Bi[0][0], aR);                                          \
    aR = MFMA_F16(AX1, Bi[0][1], aR);                                          \
    aZ = MFMA_F16(AX0, Bi[1][0], aZ);                                          \
    aZ = MFMA_F16(AX1, Bi[1][1], aZ);                                          \
    aN = MFMA_F16(AX0, Bi[2][0], aN);                                          \
    aN = MFMA_F16(AX1, Bi[2][1], aN);                                          \
    aR = MFMA_F16(Ah0, Bh[0][0], aR);                                          \
    aR = MFMA_F16(Ah1, Bh[0][1], aR);                                          \
    aZ = MFMA_F16(Ah0, Bh[1][0], aZ);                                          \
    aZ = MFMA_F16(Ah1, Bh[1][1], aZ);                                          \
    aH = MFMA_F16(Ah0, Bh[2][0], aH);                                          \
    aH = MFMA_F16(Ah1, Bh[2][1], aH);                                          \
    _Pragma("unroll") for (int rr = 0; rr < 4; ++rr) {                         \
      float rg = __builtin_amdgcn_rcpf(1.f + __builtin_amdgcn_exp2f(aR[rr])); \
      float zg = __builtin_amdgcn_rcpf(1.f + __builtin_amdgcn_exp2f(aZ[rr])); \
      float pn = aN[rr] + rg * aH[rr];                                         \
      float e2 = __builtin_amdgcn_exp2f(pn);                                   \
      float nn = 1.f - 2.f * __builtin_amdgcn_rcpf(e2 + 1.f);                  \
      h[rr] = nn + zg * (h[rr] - nn);                                          \
    }                                                                          \
    if ((T_) < 15) {                                                           \
      _Pragma("unroll") for (int rr = 0; rr < 4; ++rr) {                       \
        int row = g * 4 + rr;                                                  \
        int byte = (row * 128 + j0 * 2) ^ ((row & 7) << 4);                    \
        *(_Float16*)(wbase + byte) = (_Float16)h[rr];                          \
      }                                                                        \
    }                                                                          \
    asm volatile("s_waitcnt lgkmcnt(0)" ::: "memory");                         \
    __builtin_amdgcn_s_barrier();                                              \
    __builtin_amdgcn_sched_barrier(0);                                         \
    AX0 = NX0;                                                                 \
    AX1 = NX1;                                                                 \
  }

  for (int t = 0; t < 16; t += 2) {
    GRU_STEP(t, 0, AxA0, AxA1);
    GRU_STEP(t + 1, 1, AxB0, AxB1);
  }
#undef GRU_STEP

  {
    float s = h[0] + h[1] + h[2] + h[3];
    s += __shfl_xor(s, 16);
    s += __shfl_xor(s, 32);
    if (g == 0) genc[gph * 64 + j0] = s * 0.0625f;
  }
}

// ---------------- Kernel 3: fused BN stats + BN apply + MLP + log_softmax ----------------
__global__ __launch_bounds__(256) void k_post(const float* __restrict__ genc,
                                              const float* __restrict__ gamma,
                                              const float* __restrict__ beta,
                                              const float* __restrict__ W1,
                                              const float* __restrict__ b1,
                                              const float* __restrict__ W2,
                                              const float* __restrict__ b2,
                                              float* __restrict__ out) {
  __shared__ float sum_s[4][64], sq_s[4][64], sc[64], sh[64];
  __shared__ float w1[32 * 64], w2[10 * 32], bb1[32], bb2[10];
  const int tid = threadIdx.x;
  const int j = tid & 63, grp = tid >> 6;

  float s = 0.f, q = 0.f;
  for (int rr = 0; rr < 256; ++rr) {
    float v = genc[(grp * 256 + rr) * 64 + j];
    s += v;
    q += v * v;
  }
  sum_s[grp][j] = s;
  sq_s[grp][j] = q;

  for (int i = tid; i < 32 * 64; i += 256) w1[i] = W1[i];
  for (int i = tid; i < 10 * 32; i += 256) w2[i] = W2[i];
  if (tid < 32) bb1[tid] = b1[tid];
  if (tid >= 32 && tid < 42) bb2[tid - 32] = b2[tid - 32];
  __syncthreads();

  if (grp == 0) {
    float S = sum_s[0][j] + sum_s[1][j] + sum_s[2][j] + sum_s[3][j];
    float Q = sq_s[0][j] + sq_s[1][j] + sq_s[2][j] + sq_s[3][j];
    float mean = S * (1.f / 1024.f);
    float var = Q * (1.f / 1024.f) - mean * mean;
    float rstd = rsqrtf(var + 1e-5f);
    float scv = gamma[j] * rstd;
    sc[j] = scv;
    sh[j] = beta[j] - mean * scv;
  }
  __syncthreads();

  const int row = blockIdx.x * 256 + tid;
  float gn[64];
  const f32x4* gp = (const f32x4*)(genc + row * 64);
#pragma unroll
  for (int jq = 0; jq < 16; ++jq) {
    f32x4 v = gp[jq];
#pragma unroll
    for (int e = 0; e < 4; ++e) gn[jq * 4 + e] = v[e] * sc[jq * 4 + e] + sh[jq * 4 + e];
  }

  float h1[32];
#pragma unroll
  for (int i = 0; i < 32; ++i) {
    float a = bb1[i];
#pragma unroll
    for (int jj = 0; jj < 64; ++jj) a += w1[i * 64 + jj] * gn[jj];
    h1[i] = fmaxf(a, 0.f);
  }

  float lg[10];
  float mx = -1e30f;
#pragma unroll
  for (int c = 0; c < 10; ++c) {
    float a = bb2[c];
#pragma unroll
    for (int i = 0; i < 32; ++i) a += w2[c * 32 + i] * h1[i];
    lg[c] = a;
    mx = fmaxf(mx, a);
  }
  float se = 0.f;
#pragma unroll
  for (int c = 0; c < 10; ++c) se += __expf(lg[c] - mx);
  float lse = mx + __logf(se);
#pragma unroll
  for (int c = 0; c < 10; ++c) out[row * 10 + c] = lg[c] - lse;
}

// ---------------- host launcher ----------------
extern "C" void kernel_launch(void* const* d_in, const int* in_sizes, int n_in,
                              void* d_out, int out_size, void* d_ws, size_t ws_size,
                              hipStream_t stream) {
  const float* x = (const float*)d_in[0];
  const int* walks = (const int*)d_in[1];
  const float* Wenc = (const float*)d_in[3];
  const float* benc = (const float*)d_in[4];
  const float* Wih = (const float*)d_in[5];
  const float* Whh = (const float*)d_in[6];
  const float* bih = (const float*)d_in[7];
  const float* bhh = (const float*)d_in[8];
  const float* gamma = (const float*)d_in[9];
  const float* beta = (const float*)d_in[10];
  const float* W1 = (const float*)d_in[11];
  const float* b1 = (const float*)d_in[12];
  const float* W2 = (const float*)d_in[13];
  const float* b2 = (const float*)d_in[14];
  float* out = (float*)d_out;

  char* ws = (char*)d_ws;
  _Float16* xenc = (_Float16*)ws;         // 25,600,000 B
  float* genc = (float*)(ws + 25600000);  // 262,144 B

  // R18: R15 baseline + exp2-prescaled gru weights (single attributable change).
  k_enc<<<dim3(GSTRIDE), dim3(256), 0, stream>>>(x, Wenc, benc, xenc);
  k_gru<<<dim3(512), dim3(512), 0, stream>>>(xenc, walks, Wih, Whh, bih, bhh, genc);
  k_post<<<dim3(4), dim3(256), 0, stream>>>(genc, gamma, beta, W1, b1, W2, b2, out);
}